// Round 2
// baseline (1581.749 us; speedup 1.0000x reference)
//
#include <hip/hip_runtime.h>

#define NPTS 400000
#define KK 27
#define CC 32
#define EPSV 1e-5f

// ---------------------------------------------------------------------------
// conv: out[n,d] = b[d] + sum_{k,c} mask[n,k] * x[nbr[n,k],c] * W[k,c,d]
// One thread per point; 32 fp32 accumulators; W indices are wave-uniform so
// the compiler emits scalar (constant-cache) loads for W. Fused BN-stat
// partial reduction (sum, sumsq per channel) via wave shuffle + LDS + atomics.
// NOTE: harness passes bool inputs as int32 ("integer -> const int*").
// ---------------------------------------------------------------------------
__global__ __launch_bounds__(256) void conv_kernel(
    const float* __restrict__ x,
    const float* __restrict__ W,            // [K][C][C]
    const float* __restrict__ b,            // [C]
    const int* __restrict__ nbr,            // [N][K]
    const int* __restrict__ mask,           // [N][K] int32 0/1
    float* __restrict__ out,                // [N][C]
    float* __restrict__ sums)               // [64]: sum[0:32], sumsq[32:64]
{
    const int n = blockIdx.x * 256 + threadIdx.x;
    const bool valid = n < NPTS;
    const int n0 = valid ? n : 0;

    float acc[CC];
#pragma unroll
    for (int d = 0; d < CC; ++d) acc[d] = b[d];

    const int* nrow = nbr + (size_t)n0 * KK;
    const int* mrow = mask + (size_t)n0 * KK;

    for (int k = 0; k < KK; ++k) {
        const int idx = nrow[k];
        const bool m = valid && (mrow[k] != 0);
        float4 xv[8];
        if (m) {
            const float4* xr = (const float4*)(x + (size_t)idx * CC);
#pragma unroll
            for (int j = 0; j < 8; ++j) xv[j] = xr[j];
        } else {
#pragma unroll
            for (int j = 0; j < 8; ++j) xv[j] = make_float4(0.f, 0.f, 0.f, 0.f);
        }
        const float* Wk = W + k * CC * CC;
        const float* xf = (const float*)xv;
#pragma unroll
        for (int c = 0; c < CC; ++c) {
            const float xc = xf[c];
#pragma unroll
            for (int d = 0; d < CC; ++d)
                acc[d] = fmaf(xc, Wk[c * CC + d], acc[d]);
        }
    }

    if (valid) {
        float4* orow = (float4*)(out + (size_t)n * CC);
#pragma unroll
        for (int j = 0; j < 8; ++j)
            orow[j] = make_float4(acc[4 * j + 0], acc[4 * j + 1],
                                  acc[4 * j + 2], acc[4 * j + 3]);
    }

    // ---- fused BN statistics: per-block partials -> global atomics ----
    const int lane = threadIdx.x & 63;
    const int wv = threadIdx.x >> 6;
    __shared__ float rs[4][CC];
    __shared__ float rq[4][CC];
#pragma unroll
    for (int d = 0; d < CC; ++d) {
        const float v = valid ? acc[d] : 0.f;
        float s = v, q = v * v;
#pragma unroll
        for (int o = 32; o > 0; o >>= 1) {
            s += __shfl_down(s, o, 64);
            q += __shfl_down(q, o, 64);
        }
        if (lane == 0) { rs[wv][d] = s; rq[wv][d] = q; }
    }
    __syncthreads();
    if (threadIdx.x < CC) {
        const int d = threadIdx.x;
        const float s = rs[0][d] + rs[1][d] + rs[2][d] + rs[3][d];
        const float q = rq[0][d] + rq[1][d] + rq[2][d] + rq[3][d];
        atomicAdd(&sums[d], s);
        atomicAdd(&sums[CC + d], q);
    }
}

// ---------------------------------------------------------------------------
// BN + ReLU, in place. var = E[h^2] - E[h]^2 (no cancellation: var~0.5).
// ---------------------------------------------------------------------------
__global__ __launch_bounds__(256) void bn_relu_kernel(
    float* __restrict__ buf, const float* __restrict__ sums,
    const float* __restrict__ gamma, const float* __restrict__ beta)
{
    const size_t i = (size_t)blockIdx.x * 256 + threadIdx.x; // float4 index
    const size_t base = i * 4;
    if (base >= (size_t)NPTS * CC) return;
    const int d0 = (int)(base & (CC - 1));
    float4 v = ((const float4*)buf)[i];
    float r[4] = {v.x, v.y, v.z, v.w};
#pragma unroll
    for (int j = 0; j < 4; ++j) {
        const int d = d0 + j;
        const float mean = sums[d] * (1.f / NPTS);
        const float var = sums[CC + d] * (1.f / NPTS) - mean * mean;
        const float sc = gamma[d] * rsqrtf(var + EPSV);
        const float t = (r[j] - mean) * sc + beta[d];
        r[j] = fmaxf(t, 0.f);
    }
    ((float4*)buf)[i] = make_float4(r[0], r[1], r[2], r[3]);
}

// ---------------------------------------------------------------------------
// BN + residual + ReLU, in place on d_out, residual read from x.
// ---------------------------------------------------------------------------
__global__ __launch_bounds__(256) void bn_res_relu_kernel(
    float* __restrict__ out, const float* __restrict__ sums,
    const float* __restrict__ gamma, const float* __restrict__ beta,
    const float* __restrict__ x)
{
    const size_t i = (size_t)blockIdx.x * 256 + threadIdx.x; // float4 index
    const size_t base = i * 4;
    if (base >= (size_t)NPTS * CC) return;
    const int d0 = (int)(base & (CC - 1));
    float4 v = ((const float4*)out)[i];
    float4 rx = ((const float4*)x)[i];
    float r[4] = {v.x, v.y, v.z, v.w};
    const float rxf[4] = {rx.x, rx.y, rx.z, rx.w};
#pragma unroll
    for (int j = 0; j < 4; ++j) {
        const int d = d0 + j;
        const float mean = sums[d] * (1.f / NPTS);
        const float var = sums[CC + d] * (1.f / NPTS) - mean * mean;
        const float sc = gamma[d] * rsqrtf(var + EPSV);
        const float t = (r[j] - mean) * sc + beta[d] + rxf[j];
        r[j] = fmaxf(t, 0.f);
    }
    ((float4*)out)[i] = make_float4(r[0], r[1], r[2], r[3]);
}

extern "C" void kernel_launch(void* const* d_in, const int* in_sizes, int n_in,
                              void* d_out, int out_size, void* d_ws, size_t ws_size,
                              hipStream_t stream) {
    const float* x     = (const float*)d_in[0];
    const float* W1    = (const float*)d_in[1];
    const float* b1    = (const float*)d_in[2];
    const float* g1    = (const float*)d_in[3];
    const float* be1   = (const float*)d_in[4];
    const float* W2    = (const float*)d_in[5];
    const float* b2    = (const float*)d_in[6];
    const float* g2    = (const float*)d_in[7];
    const float* be2   = (const float*)d_in[8];
    const int* nbr1    = (const int*)d_in[9];
    const int* mask1   = (const int*)d_in[10];
    const int* nbr2    = (const int*)d_in[11];
    const int* mask2   = (const int*)d_in[12];

    float* out  = (float*)d_out;
    float* sums = (float*)d_ws;                      // 128 floats (zeroed below)
    float* buf  = (float*)((char*)d_ws + 1024);      // [N][C] intermediate

    hipMemsetAsync(d_ws, 0, 1024, stream);

    const int conv_blocks = (NPTS + 255) / 256;      // 1563
    const int ew_blocks   = (NPTS * CC / 4 + 255) / 256; // 12500

    conv_kernel<<<conv_blocks, 256, 0, stream>>>(x, W1, b1, nbr1, mask1, buf, sums);
    bn_relu_kernel<<<ew_blocks, 256, 0, stream>>>(buf, sums, g1, be1);
    conv_kernel<<<conv_blocks, 256, 0, stream>>>(buf, W2, b2, nbr2, mask2, out, sums + 64);
    bn_res_relu_kernel<<<ew_blocks, 256, 0, stream>>>(out, sums + 64, g2, be2, x);
}

// Round 3
// 639.308 us; speedup vs baseline: 2.4742x; 2.4742x over previous
//
#include <hip/hip_runtime.h>

#define NPTS 400000
#define KK 27
#define CC 32
#define EPSV 1e-5f

using bf8_t = __attribute__((ext_vector_type(8))) __bf16;
using f4_t  = __attribute__((ext_vector_type(4))) float;
using us8_t = __attribute__((ext_vector_type(8))) unsigned short;

__device__ __forceinline__ unsigned short f2bf(float f) {
    unsigned int u = __float_as_uint(f);
    u += 0x7FFF + ((u >> 16) & 1u);   // RNE to bf16
    return (unsigned short)(u >> 16);
}

// ---------------------------------------------------------------------------
// Pack masks into one 27-bit word per point (both convs in one pass).
// ---------------------------------------------------------------------------
__global__ __launch_bounds__(256) void prep_bits(
    const int* __restrict__ m1, const int* __restrict__ m2,
    unsigned int* __restrict__ b1, unsigned int* __restrict__ b2)
{
    const int p = blockIdx.x * 256 + threadIdx.x;
    if (p >= NPTS) return;
    const int* r1 = m1 + (size_t)p * KK;
    const int* r2 = m2 + (size_t)p * KK;
    unsigned int v1 = 0, v2 = 0;
#pragma unroll
    for (int k = 0; k < KK; ++k) {
        v1 |= (r1[k] != 0 ? 1u : 0u) << k;
        v2 |= (r2[k] != 0 ? 1u : 0u) << k;
    }
    b1[p] = v1; b2[p] = v2;
}

// ---------------------------------------------------------------------------
// x fp32 -> bf16 rows (row = 64B).
// ---------------------------------------------------------------------------
__global__ __launch_bounds__(256) void cvt_x(
    const float* __restrict__ x, unsigned short* __restrict__ xb)
{
    const size_t base = ((size_t)blockIdx.x * 256 + threadIdx.x) * 8;
    if (base >= (size_t)NPTS * CC) return;
    const f4_t v0 = *(const f4_t*)(x + base);
    const f4_t v1 = *(const f4_t*)(x + base + 4);
    us8_t o;
#pragma unroll
    for (int j = 0; j < 8; ++j) o[j] = f2bf(j < 4 ? v0[j] : v1[j - 4]);
    *(us8_t*)(xb + base) = o;
}

// ---------------------------------------------------------------------------
// W [k][c][d] fp32 -> Wt [k][d][c] bf16 (transposed so B-frags are contiguous).
// ---------------------------------------------------------------------------
__global__ __launch_bounds__(256) void cvt_w(
    const float* __restrict__ W1, const float* __restrict__ W2,
    unsigned short* __restrict__ Wt1, unsigned short* __restrict__ Wt2)
{
    const int id = blockIdx.x * 256 + threadIdx.x;
    if (id >= 2 * KK * CC * CC) return;
    const int which = id >= KK * CC * CC;
    const int t = which ? id - KK * CC * CC : id;
    const int k = t >> 10, d = (t >> 5) & 31, c = t & 31;
    const float* W = which ? W2 : W1;
    unsigned short* Wt = which ? Wt2 : Wt1;
    Wt[t] = f2bf(W[k * 1024 + c * CC + d]);
}

// ---------------------------------------------------------------------------
// Gather-GEMM via MFMA. Wave owns 32 points (2 groups of 16). Gathered rows
// land DIRECTLY in A-frag layout: lane l loads 16B of row (l&15) at byte
// offset (l>>4)*16 -> 4 lanes cover one 64B bf16 row, fully coalesced.
// Mask-predicated loads skip transactions for absent neighbors.
// Fused BN stats (sum, sumsq per channel).
// ---------------------------------------------------------------------------
__global__ __launch_bounds__(256) void conv_mfma(
    const unsigned short* __restrict__ xb,   // [N][32] bf16
    const unsigned short* __restrict__ Wt,   // [27][32(d)][32(c)] bf16
    const float* __restrict__ bias,          // [32]
    const int* __restrict__ nbr,             // [N][27]
    const unsigned int* __restrict__ bits,   // [N] 27-bit masks
    float* __restrict__ out,                 // [N][32] fp32
    float* __restrict__ sums)                // [64]: sum, sumsq
{
    const int wave = threadIdx.x >> 6;
    const int lane = threadIdx.x & 63;
    const int m = lane & 15;
    const int q = lane >> 4;
    const int p0 = blockIdx.x * 128 + wave * 32;   // 3125 blocks * 128 = N exactly

    const int pA = p0 + m, pB = p0 + 16 + m;
    const unsigned int bA = bits[pA], bB = bits[pB];
    const int* nrA = nbr + (size_t)pA * KK;
    const int* nrB = nbr + (size_t)pB * KK;

    f4_t acc00 = {}, acc01 = {}, acc10 = {}, acc11 = {};

#pragma unroll
    for (int k = 0; k < KK; ++k) {
        const int i0 = nrA[k];
        const int i1 = nrB[k];
        bf8_t a0 = {}, a1 = {};
        if ((bA >> k) & 1u) a0 = *(const bf8_t*)(xb + i0 * CC + q * 8);
        if ((bB >> k) & 1u) a1 = *(const bf8_t*)(xb + i1 * CC + q * 8);
        const unsigned short* wk = Wt + k * (CC * CC) + q * 8;
        const bf8_t w0 = *(const bf8_t*)(wk + m * CC);          // d = 0..15
        const bf8_t w1 = *(const bf8_t*)(wk + (m + 16) * CC);   // d = 16..31
        acc00 = __builtin_amdgcn_mfma_f32_16x16x32_bf16(a0, w0, acc00, 0, 0, 0);
        acc01 = __builtin_amdgcn_mfma_f32_16x16x32_bf16(a0, w1, acc01, 0, 0, 0);
        acc10 = __builtin_amdgcn_mfma_f32_16x16x32_bf16(a1, w0, acc10, 0, 0, 0);
        acc11 = __builtin_amdgcn_mfma_f32_16x16x32_bf16(a1, w1, acc11, 0, 0, 0);
    }

    // epilogue: D[row=(q*4+r)][col=m] -> point p0+16g+q*4+r, channel m+16h
    const float b0 = bias[m], b1 = bias[m + 16];
    float s0 = 0.f, q0 = 0.f, s1 = 0.f, q1 = 0.f;
#pragma unroll
    for (int g = 0; g < 2; ++g) {
        const f4_t t0v = g ? acc10 : acc00;
        const f4_t t1v = g ? acc11 : acc01;
        const int prow = p0 + 16 * g + q * 4;
#pragma unroll
        for (int r = 0; r < 4; ++r) {
            const float t0 = t0v[r] + b0;
            const float t1 = t1v[r] + b1;
            out[(size_t)(prow + r) * CC + m] = t0;
            out[(size_t)(prow + r) * CC + m + 16] = t1;
            s0 += t0; q0 += t0 * t0;
            s1 += t1; q1 += t1 * t1;
        }
    }
    s0 += __shfl_down(s0, 32, 64); s0 += __shfl_down(s0, 16, 64);
    q0 += __shfl_down(q0, 32, 64); q0 += __shfl_down(q0, 16, 64);
    s1 += __shfl_down(s1, 32, 64); s1 += __shfl_down(s1, 16, 64);
    q1 += __shfl_down(q1, 32, 64); q1 += __shfl_down(q1, 16, 64);

    __shared__ float rs[4][CC], rq[4][CC];
    if (lane < 16) {
        rs[wave][m] = s0;      rq[wave][m] = q0;
        rs[wave][m + 16] = s1; rq[wave][m + 16] = q1;
    }
    __syncthreads();
    if (threadIdx.x < CC) {
        const int d = threadIdx.x;
        atomicAdd(&sums[d],      rs[0][d] + rs[1][d] + rs[2][d] + rs[3][d]);
        atomicAdd(&sums[CC + d], rq[0][d] + rq[1][d] + rq[2][d] + rq[3][d]);
    }
}

// ---------------------------------------------------------------------------
// BN + ReLU on fp32 h, write bf16 rows for conv2's gather.
// ---------------------------------------------------------------------------
__global__ __launch_bounds__(256) void bn_relu_bf16(
    const float* __restrict__ h, const float* __restrict__ sums,
    const float* __restrict__ gamma, const float* __restrict__ beta,
    unsigned short* __restrict__ buf)
{
    const size_t base = ((size_t)blockIdx.x * 256 + threadIdx.x) * 8;
    if (base >= (size_t)NPTS * CC) return;
    const int d0 = (int)(base & (CC - 1));
    const f4_t v0 = *(const f4_t*)(h + base);
    const f4_t v1 = *(const f4_t*)(h + base + 4);
    us8_t o;
#pragma unroll
    for (int j = 0; j < 8; ++j) {
        const int d = d0 + j;
        const float mean = sums[d] * (1.f / NPTS);
        const float var = sums[CC + d] * (1.f / NPTS) - mean * mean;
        const float sc = gamma[d] * rsqrtf(var + EPSV);
        const float x = (j < 4 ? v0[j] : v1[j - 4]);
        o[j] = f2bf(fmaxf((x - mean) * sc + beta[d], 0.f));
    }
    *(us8_t*)(buf + base) = o;
}

// ---------------------------------------------------------------------------
// BN + residual + ReLU, in place on d_out.
// ---------------------------------------------------------------------------
__global__ __launch_bounds__(256) void bn_res_relu_kernel(
    float* __restrict__ out, const float* __restrict__ sums,
    const float* __restrict__ gamma, const float* __restrict__ beta,
    const float* __restrict__ x)
{
    const size_t i = (size_t)blockIdx.x * 256 + threadIdx.x;
    const size_t base = i * 4;
    if (base >= (size_t)NPTS * CC) return;
    const int d0 = (int)(base & (CC - 1));
    float4 v = ((const float4*)out)[i];
    float4 rx = ((const float4*)x)[i];
    float r[4] = {v.x, v.y, v.z, v.w};
    const float rxf[4] = {rx.x, rx.y, rx.z, rx.w};
#pragma unroll
    for (int j = 0; j < 4; ++j) {
        const int d = d0 + j;
        const float mean = sums[d] * (1.f / NPTS);
        const float var = sums[CC + d] * (1.f / NPTS) - mean * mean;
        const float sc = gamma[d] * rsqrtf(var + EPSV);
        r[j] = fmaxf((r[j] - mean) * sc + beta[d] + rxf[j], 0.f);
    }
    ((float4*)out)[i] = make_float4(r[0], r[1], r[2], r[3]);
}

extern "C" void kernel_launch(void* const* d_in, const int* in_sizes, int n_in,
                              void* d_out, int out_size, void* d_ws, size_t ws_size,
                              hipStream_t stream) {
    const float* x   = (const float*)d_in[0];
    const float* W1  = (const float*)d_in[1];
    const float* b1  = (const float*)d_in[2];
    const float* g1  = (const float*)d_in[3];
    const float* be1 = (const float*)d_in[4];
    const float* W2  = (const float*)d_in[5];
    const float* b2  = (const float*)d_in[6];
    const float* g2  = (const float*)d_in[7];
    const float* be2 = (const float*)d_in[8];
    const int* nbr1  = (const int*)d_in[9];
    const int* mask1 = (const int*)d_in[10];
    const int* nbr2  = (const int*)d_in[11];
    const int* mask2 = (const int*)d_in[12];

    float* out = (float*)d_out;

    // workspace layout (~29 MB): sums | bits1 | bits2 | xbuf(bf16, reused) | Wt1 | Wt2
    float* sums          = (float*)d_ws;                                   // 256 floats
    unsigned int* bits1  = (unsigned int*)((char*)d_ws + 1024);
    unsigned int* bits2  = bits1 + NPTS;
    unsigned short* xbuf = (unsigned short*)((char*)d_ws + 1024 + 2 * (size_t)NPTS * 4);
    unsigned short* Wt1  = xbuf + (size_t)NPTS * CC;
    unsigned short* Wt2  = Wt1 + KK * CC * CC;

    hipMemsetAsync(d_ws, 0, 1024, stream);  // zero both sum sets

    prep_bits<<<(NPTS + 255) / 256, 256, 0, stream>>>(mask1, mask2, bits1, bits2);
    cvt_x<<<(NPTS * CC / 8 + 255) / 256, 256, 0, stream>>>(x, xbuf);
    cvt_w<<<(2 * KK * CC * CC + 255) / 256, 256, 0, stream>>>(W1, W2, Wt1, Wt2);

    // conv1: h1 -> d_out (fp32) + stats in sums[0:64]
    conv_mfma<<<NPTS / 128, 256, 0, stream>>>(xbuf, Wt1, b1, nbr1, bits1, out, sums);
    // BN+ReLU -> bf16 xbuf (reuse: conv1 no longer needs x in bf16)
    bn_relu_bf16<<<(NPTS * CC / 8 + 255) / 256, 256, 0, stream>>>(out, sums, g1, be1, xbuf);
    // conv2: -> d_out (fp32) + stats in sums[64:128]
    conv_mfma<<<NPTS / 128, 256, 0, stream>>>(xbuf, Wt2, b2, nbr2, bits2, out, sums + 64);
    // BN + residual + ReLU in place
    bn_res_relu_kernel<<<(NPTS * CC / 4 + 255) / 256, 256, 0, stream>>>(out, sums + 64, g2, be2, x);
}

// Round 4
// 607.885 us; speedup vs baseline: 2.6021x; 1.0517x over previous
//
#include <hip/hip_runtime.h>

#define NPTS 400000
#define KK 27
#define CC 32
#define EPSV 1e-5f

using bf8_t = __attribute__((ext_vector_type(8))) __bf16;
using f4_t  = __attribute__((ext_vector_type(4))) float;
using us8_t = __attribute__((ext_vector_type(8))) unsigned short;

__device__ __forceinline__ unsigned short f2bf(float f) {
    unsigned int u = __float_as_uint(f);
    u += 0x7FFF + ((u >> 16) & 1u);   // RNE to bf16
    return (unsigned short)(u >> 16);
}

// ---------------------------------------------------------------------------
// prep_fuse: nbr[n][k] + mask[n][k] -> fT[k][n] = mask ? idx : -1.
// Coalesced int4 staging into LDS, transposed write-out (stride 27 is odd ->
// LDS bank-conflict-free). Kills the 16-lines-per-instr nbr reads in conv.
// ---------------------------------------------------------------------------
__global__ __launch_bounds__(256) void prep_fuse(
    const int* __restrict__ nbr, const int* __restrict__ mask,
    int* __restrict__ fT)
{
    __shared__ int ln[256 * KK];
    __shared__ int lm[256 * KK];
    const int t = threadIdx.x;
    const int P0 = blockIdx.x * 256;
    const size_t base = (size_t)P0 * KK;
    const int cnt = min(256 * KK, (NPTS - P0) * KK);
    const int cnt4 = cnt >> 2;
    const int4* n4 = (const int4*)(nbr + base);   // base*4 bytes: 27648-aligned
    const int4* m4 = (const int4*)(mask + base);
    for (int i = t; i < cnt4; i += 256) {
        ((int4*)ln)[i] = n4[i];
        ((int4*)lm)[i] = m4[i];
    }
    for (int i = (cnt4 << 2) + t; i < cnt; i += 256) {
        ln[i] = nbr[base + i];
        lm[i] = mask[base + i];
    }
    __syncthreads();
    const int p = P0 + t;
    if (p < NPTS) {
#pragma unroll
        for (int k = 0; k < KK; ++k) {
            const int idx = ln[t * KK + k];
            const int mv = lm[t * KK + k];
            fT[(size_t)k * NPTS + p] = mv ? idx : -1;
        }
    }
}

// ---------------------------------------------------------------------------
// x fp32 -> bf16 rows (row = 64B).
// ---------------------------------------------------------------------------
__global__ __launch_bounds__(256) void cvt_x(
    const float* __restrict__ x, unsigned short* __restrict__ xb)
{
    const size_t base = ((size_t)blockIdx.x * 256 + threadIdx.x) * 8;
    if (base >= (size_t)NPTS * CC) return;
    const f4_t v0 = *(const f4_t*)(x + base);
    const f4_t v1 = *(const f4_t*)(x + base + 4);
    us8_t o;
#pragma unroll
    for (int j = 0; j < 8; ++j) o[j] = f2bf(j < 4 ? v0[j] : v1[j - 4]);
    *(us8_t*)(xb + base) = o;
}

// ---------------------------------------------------------------------------
// W [k][c][d] fp32 -> Wt [k][d][c] bf16 (transposed so B-frags are contiguous).
// ---------------------------------------------------------------------------
__global__ __launch_bounds__(256) void cvt_w(
    const float* __restrict__ W1, const float* __restrict__ W2,
    unsigned short* __restrict__ Wt1, unsigned short* __restrict__ Wt2)
{
    const int id = blockIdx.x * 256 + threadIdx.x;
    if (id >= 2 * KK * CC * CC) return;
    const int which = id >= KK * CC * CC;
    const int t = which ? id - KK * CC * CC : id;
    const int k = t >> 10, d = (t >> 5) & 31, c = t & 31;
    const float* W = which ? W2 : W1;
    unsigned short* Wt = which ? Wt2 : Wt1;
    Wt[t] = f2bf(W[k * 1024 + c * CC + d]);
}

// ---------------------------------------------------------------------------
// Gather-GEMM via MFMA, 4-deep software-pipelined gather.
// Wave owns 32 points (2 groups of 16). Lane l loads 16B of row (l&15) at
// byte offset (l>>4)*16 -> 4 lanes cover one 64B bf16 row, coalesced, landing
// directly in A-frag layout. Index loads are 1 cache line per instr (fT is
// [k][n]); idx<0 means masked (no transaction issued).
// ---------------------------------------------------------------------------
__global__ __launch_bounds__(256, 4) void conv_mfma(
    const unsigned short* __restrict__ xb,   // [N][32] bf16
    const unsigned short* __restrict__ Wt,   // [27][32(d)][32(c)] bf16
    const float* __restrict__ bias,          // [32]
    const int* __restrict__ fT,              // [27][N] fused idx/-1
    float* __restrict__ out,                 // [N][32] fp32
    float* __restrict__ sums)                // [64]: sum, sumsq
{
    const int wave = threadIdx.x >> 6;
    const int lane = threadIdx.x & 63;
    const int m = lane & 15;
    const int q = lane >> 4;
    const int p0 = blockIdx.x * 128 + wave * 32;   // 3125 blocks * 128 = N
    const int pA = p0 + m, pB = pA + 16;

    f4_t acc00 = {}, acc01 = {}, acc10 = {}, acc11 = {};
    bf8_t A0[4], A1[4];

#pragma unroll
    for (int k = 0; k < 4; ++k) {
        const int i0 = fT[(size_t)k * NPTS + pA];
        const int i1 = fT[(size_t)k * NPTS + pB];
        bf8_t t0 = {}, t1 = {};
        if (i0 >= 0) t0 = *(const bf8_t*)(xb + i0 * CC + q * 8);
        if (i1 >= 0) t1 = *(const bf8_t*)(xb + i1 * CC + q * 8);
        A0[k] = t0; A1[k] = t1;
    }

#pragma unroll
    for (int k = 0; k < KK; ++k) {
        const bf8_t a0 = A0[k & 3];
        const bf8_t a1 = A1[k & 3];
        if (k + 4 < KK) {
            const int i0 = fT[(size_t)(k + 4) * NPTS + pA];
            const int i1 = fT[(size_t)(k + 4) * NPTS + pB];
            bf8_t t0 = {}, t1 = {};
            if (i0 >= 0) t0 = *(const bf8_t*)(xb + i0 * CC + q * 8);
            if (i1 >= 0) t1 = *(const bf8_t*)(xb + i1 * CC + q * 8);
            A0[k & 3] = t0; A1[k & 3] = t1;
        }
        const unsigned short* wk = Wt + k * (CC * CC) + q * 8;
        const bf8_t w0 = *(const bf8_t*)(wk + m * CC);          // d = 0..15
        const bf8_t w1 = *(const bf8_t*)(wk + (m + 16) * CC);   // d = 16..31
        acc00 = __builtin_amdgcn_mfma_f32_16x16x32_bf16(a0, w0, acc00, 0, 0, 0);
        acc01 = __builtin_amdgcn_mfma_f32_16x16x32_bf16(a0, w1, acc01, 0, 0, 0);
        acc10 = __builtin_amdgcn_mfma_f32_16x16x32_bf16(a1, w0, acc10, 0, 0, 0);
        acc11 = __builtin_amdgcn_mfma_f32_16x16x32_bf16(a1, w1, acc11, 0, 0, 0);
    }

    // epilogue: D[row=(q*4+r)][col=m] -> point p0+16g+q*4+r, channel m(+16)
    const float b0 = bias[m], b1 = bias[m + 16];
    float s0 = 0.f, q0 = 0.f, s1 = 0.f, q1 = 0.f;
#pragma unroll
    for (int g = 0; g < 2; ++g) {
        const f4_t t0v = g ? acc10 : acc00;
        const f4_t t1v = g ? acc11 : acc01;
        const int prow = p0 + 16 * g + q * 4;
#pragma unroll
        for (int r = 0; r < 4; ++r) {
            const float t0 = t0v[r] + b0;
            const float t1 = t1v[r] + b1;
            out[(size_t)(prow + r) * CC + m] = t0;
            out[(size_t)(prow + r) * CC + m + 16] = t1;
            s0 += t0; q0 += t0 * t0;
            s1 += t1; q1 += t1 * t1;
        }
    }
    s0 += __shfl_down(s0, 32, 64); s0 += __shfl_down(s0, 16, 64);
    q0 += __shfl_down(q0, 32, 64); q0 += __shfl_down(q0, 16, 64);
    s1 += __shfl_down(s1, 32, 64); s1 += __shfl_down(s1, 16, 64);
    q1 += __shfl_down(q1, 32, 64); q1 += __shfl_down(q1, 16, 64);

    __shared__ float rs[4][CC], rq[4][CC];
    if (lane < 16) {
        rs[wave][m] = s0;      rq[wave][m] = q0;
        rs[wave][m + 16] = s1; rq[wave][m + 16] = q1;
    }
    __syncthreads();
    if (threadIdx.x < CC) {
        const int d = threadIdx.x;
        atomicAdd(&sums[d],      rs[0][d] + rs[1][d] + rs[2][d] + rs[3][d]);
        atomicAdd(&sums[CC + d], rq[0][d] + rq[1][d] + rq[2][d] + rq[3][d]);
    }
}

// ---------------------------------------------------------------------------
// BN + ReLU on fp32 h, write bf16 rows for conv2's gather.
// ---------------------------------------------------------------------------
__global__ __launch_bounds__(256) void bn_relu_bf16(
    const float* __restrict__ h, const float* __restrict__ sums,
    const float* __restrict__ gamma, const float* __restrict__ beta,
    unsigned short* __restrict__ buf)
{
    const size_t base = ((size_t)blockIdx.x * 256 + threadIdx.x) * 8;
    if (base >= (size_t)NPTS * CC) return;
    const int d0 = (int)(base & (CC - 1));
    const f4_t v0 = *(const f4_t*)(h + base);
    const f4_t v1 = *(const f4_t*)(h + base + 4);
    us8_t o;
#pragma unroll
    for (int j = 0; j < 8; ++j) {
        const int d = d0 + j;
        const float mean = sums[d] * (1.f / NPTS);
        const float var = sums[CC + d] * (1.f / NPTS) - mean * mean;
        const float sc = gamma[d] * rsqrtf(var + EPSV);
        const float x = (j < 4 ? v0[j] : v1[j - 4]);
        o[j] = f2bf(fmaxf((x - mean) * sc + beta[d], 0.f));
    }
    *(us8_t*)(buf + base) = o;
}

// ---------------------------------------------------------------------------
// BN + residual + ReLU, in place on d_out.
// ---------------------------------------------------------------------------
__global__ __launch_bounds__(256) void bn_res_relu_kernel(
    float* __restrict__ out, const float* __restrict__ sums,
    const float* __restrict__ gamma, const float* __restrict__ beta,
    const float* __restrict__ x)
{
    const size_t i = (size_t)blockIdx.x * 256 + threadIdx.x;
    const size_t base = i * 4;
    if (base >= (size_t)NPTS * CC) return;
    const int d0 = (int)(base & (CC - 1));
    float4 v = ((const float4*)out)[i];
    float4 rx = ((const float4*)x)[i];
    float r[4] = {v.x, v.y, v.z, v.w};
    const float rxf[4] = {rx.x, rx.y, rx.z, rx.w};
#pragma unroll
    for (int j = 0; j < 4; ++j) {
        const int d = d0 + j;
        const float mean = sums[d] * (1.f / NPTS);
        const float var = sums[CC + d] * (1.f / NPTS) - mean * mean;
        const float sc = gamma[d] * rsqrtf(var + EPSV);
        r[j] = fmaxf((r[j] - mean) * sc + beta[d] + rxf[j], 0.f);
    }
    ((float4*)out)[i] = make_float4(r[0], r[1], r[2], r[3]);
}

extern "C" void kernel_launch(void* const* d_in, const int* in_sizes, int n_in,
                              void* d_out, int out_size, void* d_ws, size_t ws_size,
                              hipStream_t stream) {
    const float* x   = (const float*)d_in[0];
    const float* W1  = (const float*)d_in[1];
    const float* b1  = (const float*)d_in[2];
    const float* g1  = (const float*)d_in[3];
    const float* be1 = (const float*)d_in[4];
    const float* W2  = (const float*)d_in[5];
    const float* b2  = (const float*)d_in[6];
    const float* g2  = (const float*)d_in[7];
    const float* be2 = (const float*)d_in[8];
    const int* nbr1  = (const int*)d_in[9];
    const int* mask1 = (const int*)d_in[10];
    const int* nbr2  = (const int*)d_in[11];
    const int* mask2 = (const int*)d_in[12];

    float* out = (float*)d_out;

    // workspace (~69 MB): sums | fT (shared by both convs) | xbuf | Wt1 | Wt2
    float* sums          = (float*)d_ws;                                // 256 floats
    int* fT              = (int*)((char*)d_ws + 1024);                  // 27*N ints
    unsigned short* xbuf = (unsigned short*)((char*)d_ws + 1024 + (size_t)KK * NPTS * 4);
    unsigned short* Wt1  = xbuf + (size_t)NPTS * CC;
    unsigned short* Wt2  = Wt1 + KK * CC * CC;

    hipMemsetAsync(d_ws, 0, 1024, stream);

    const int prep_blocks = (NPTS + 255) / 256;          // 1563
    const int cvt_blocks  = (NPTS * CC / 8 + 255) / 256; // 6250

    cvt_x<<<cvt_blocks, 256, 0, stream>>>(x, xbuf);
    cvt_w<<<(2 * KK * CC * CC + 255) / 256, 256, 0, stream>>>(W1, W2, Wt1, Wt2);
    prep_fuse<<<prep_blocks, 256, 0, stream>>>(nbr1, mask1, fT);

    // conv1: h1 -> d_out (fp32) + stats in sums[0:64]
    conv_mfma<<<NPTS / 128, 256, 0, stream>>>(xbuf, Wt1, b1, fT, out, sums);
    // re-fill fT for conv2 (stream-ordered after conv1)
    prep_fuse<<<prep_blocks, 256, 0, stream>>>(nbr2, mask2, fT);
    // BN+ReLU -> bf16 xbuf (reuse)
    bn_relu_bf16<<<cvt_blocks, 256, 0, stream>>>(out, sums, g1, be1, xbuf);
    // conv2: -> d_out (fp32) + stats in sums[64:128]
    conv_mfma<<<NPTS / 128, 256, 0, stream>>>(xbuf, Wt2, b2, fT, out, sums + 64);
    // BN + residual + ReLU in place
    bn_res_relu_kernel<<<(NPTS * CC / 4 + 255) / 256, 256, 0, stream>>>(out, sums + 64, g2, be2, x);
}

// Round 5
// 538.820 us; speedup vs baseline: 2.9356x; 1.1282x over previous
//
#include <hip/hip_runtime.h>

#define NPTS 400000
#define KK 27
#define CC 32
#define EPSV 1e-5f
#define LSTRIDE 29   // 27 k's padded to odd stride -> conflict-free LDS access

using bf8_t = __attribute__((ext_vector_type(8))) __bf16;
using f4_t  = __attribute__((ext_vector_type(4))) float;
using us8_t = __attribute__((ext_vector_type(8))) unsigned short;

__device__ __forceinline__ unsigned short f2bf(float f) {
    unsigned int u = __float_as_uint(f);
    u += 0x7FFF + ((u >> 16) & 1u);   // RNE to bf16
    return (unsigned short)(u >> 16);
}

// ---------------------------------------------------------------------------
// Fused conversions: blocks [0,216) transpose W1|W2 -> bf16 [k][d][c];
// remaining blocks convert x -> bf16 rows.
// ---------------------------------------------------------------------------
#define WBLOCKS 216  // 2*27*32*32 / 256
__global__ __launch_bounds__(256) void cvt_all(
    const float* __restrict__ x,
    const float* __restrict__ W1, const float* __restrict__ W2,
    unsigned short* __restrict__ xb,
    unsigned short* __restrict__ Wt1, unsigned short* __restrict__ Wt2)
{
    const int bid = blockIdx.x;
    if (bid < WBLOCKS) {
        const int id = bid * 256 + threadIdx.x;          // < 55296
        const int which = id >= KK * CC * CC;
        const int t = which ? id - KK * CC * CC : id;
        const int k = t >> 10, d = (t >> 5) & 31, c = t & 31;
        const float* W = which ? W2 : W1;
        unsigned short* Wt = which ? Wt2 : Wt1;
        Wt[t] = f2bf(W[k * 1024 + c * CC + d]);
        return;
    }
    const size_t base = ((size_t)(bid - WBLOCKS) * 256 + threadIdx.x) * 8;
    if (base >= (size_t)NPTS * CC) return;
    const f4_t v0 = *(const f4_t*)(x + base);
    const f4_t v1 = *(const f4_t*)(x + base + 4);
    us8_t o;
#pragma unroll
    for (int j = 0; j < 8; ++j) o[j] = f2bf(j < 4 ? v0[j] : v1[j - 4]);
    *(us8_t*)(xb + base) = o;
}

// ---------------------------------------------------------------------------
// Gather-GEMM via MFMA.
// - In-kernel nbr+mask staging: 128 points' rows (13.8 KB, contiguous) fused
//   to idx|-1 in LDS [p][LSTRIDE] (writes lane-consecutive; reads stride-29).
// - K-loop in 3 batches of 9: all 18 gathers of a batch issued into explicit
//   register arrays before the 36 MFMAs -> 18 outstanding loads/wave.
// - Gather lands directly in A-frag layout: lane l loads 16B of row (l&15)
//   at byte offset (l>>4)*16; 4 lanes cover one 64B bf16 row.
// - Fused BN stats (sum, sumsq per channel) via shuffle + LDS + atomics.
// ---------------------------------------------------------------------------
__global__ __launch_bounds__(256, 4) void conv_mfma(
    const unsigned short* __restrict__ xb,   // [N][32] bf16
    const unsigned short* __restrict__ Wt,   // [27][32(d)][32(c)] bf16
    const float* __restrict__ bias,          // [32]
    const int* __restrict__ nbr,             // [N][27]
    const int* __restrict__ mask,            // [N][27] int32 0/1
    float* __restrict__ out,                 // [N][32] fp32
    float* __restrict__ sums)                // [64]: sum, sumsq
{
    __shared__ int lidx[128 * LSTRIDE];      // 14848 B
    __shared__ float rs[4][CC], rq[4][CC];

    const int t = threadIdx.x;
    const int P0 = blockIdx.x * 128;         // 3125 blocks * 128 = N exactly

    // ---- stage fused indices (coalesced scalar loads, conflict-free LDS) ----
    const int* nb = nbr + (size_t)P0 * KK;
    const int* mb = mask + (size_t)P0 * KK;
    for (int i = t; i < 128 * KK; i += 256) {
        const int p = i / KK;
        const int k = i - p * KK;
        lidx[p * LSTRIDE + k] = mb[i] ? nb[i] : -1;
    }
    __syncthreads();

    const int wave = t >> 6;
    const int lane = t & 63;
    const int m = lane & 15;
    const int q = lane >> 4;
    const int p0 = P0 + wave * 32;

    const int* rowA = lidx + (wave * 32 + m) * LSTRIDE;
    const int* rowB = rowA + 16 * LSTRIDE;

    f4_t acc00 = {}, acc01 = {}, acc10 = {}, acc11 = {};

#pragma unroll
    for (int kb = 0; kb < 3; ++kb) {
        bf8_t A0[9], A1[9];
#pragma unroll
        for (int j = 0; j < 9; ++j) {
            const int i0 = rowA[kb * 9 + j];
            const int i1 = rowB[kb * 9 + j];
            bf8_t t0 = {}, t1 = {};
            if (i0 >= 0) t0 = *(const bf8_t*)(xb + i0 * CC + q * 8);
            if (i1 >= 0) t1 = *(const bf8_t*)(xb + i1 * CC + q * 8);
            A0[j] = t0; A1[j] = t1;
        }
#pragma unroll
        for (int j = 0; j < 9; ++j) {
            const unsigned short* wk = Wt + (kb * 9 + j) * (CC * CC) + q * 8;
            const bf8_t w0 = *(const bf8_t*)(wk + m * CC);          // d 0..15
            const bf8_t w1 = *(const bf8_t*)(wk + (m + 16) * CC);   // d 16..31
            acc00 = __builtin_amdgcn_mfma_f32_16x16x32_bf16(A0[j], w0, acc00, 0, 0, 0);
            acc01 = __builtin_amdgcn_mfma_f32_16x16x32_bf16(A0[j], w1, acc01, 0, 0, 0);
            acc10 = __builtin_amdgcn_mfma_f32_16x16x32_bf16(A1[j], w0, acc10, 0, 0, 0);
            acc11 = __builtin_amdgcn_mfma_f32_16x16x32_bf16(A1[j], w1, acc11, 0, 0, 0);
        }
    }

    // epilogue: D[row=(q*4+r)][col=m] -> point p0+16g+q*4+r, channel m(+16)
    const float b0 = bias[m], b1 = bias[m + 16];
    float s0 = 0.f, q0 = 0.f, s1 = 0.f, q1 = 0.f;
#pragma unroll
    for (int g = 0; g < 2; ++g) {
        const f4_t t0v = g ? acc10 : acc00;
        const f4_t t1v = g ? acc11 : acc01;
        const int prow = p0 + 16 * g + q * 4;
#pragma unroll
        for (int r = 0; r < 4; ++r) {
            const float v0 = t0v[r] + b0;
            const float v1 = t1v[r] + b1;
            out[(size_t)(prow + r) * CC + m] = v0;
            out[(size_t)(prow + r) * CC + m + 16] = v1;
            s0 += v0; q0 += v0 * v0;
            s1 += v1; q1 += v1 * v1;
        }
    }
    s0 += __shfl_down(s0, 32, 64); s0 += __shfl_down(s0, 16, 64);
    q0 += __shfl_down(q0, 32, 64); q0 += __shfl_down(q0, 16, 64);
    s1 += __shfl_down(s1, 32, 64); s1 += __shfl_down(s1, 16, 64);
    q1 += __shfl_down(q1, 32, 64); q1 += __shfl_down(q1, 16, 64);

    if (lane < 16) {
        rs[wave][m] = s0;      rq[wave][m] = q0;
        rs[wave][m + 16] = s1; rq[wave][m + 16] = q1;
    }
    __syncthreads();
    if (t < CC) {
        atomicAdd(&sums[t],      rs[0][t] + rs[1][t] + rs[2][t] + rs[3][t]);
        atomicAdd(&sums[CC + t], rq[0][t] + rq[1][t] + rq[2][t] + rq[3][t]);
    }
}

// ---------------------------------------------------------------------------
// BN + ReLU on fp32 h, write bf16 rows for conv2's gather.
// ---------------------------------------------------------------------------
__global__ __launch_bounds__(256) void bn_relu_bf16(
    const float* __restrict__ h, const float* __restrict__ sums,
    const float* __restrict__ gamma, const float* __restrict__ beta,
    unsigned short* __restrict__ buf)
{
    const size_t base = ((size_t)blockIdx.x * 256 + threadIdx.x) * 8;
    if (base >= (size_t)NPTS * CC) return;
    const int d0 = (int)(base & (CC - 1));
    const f4_t v0 = *(const f4_t*)(h + base);
    const f4_t v1 = *(const f4_t*)(h + base + 4);
    us8_t o;
#pragma unroll
    for (int j = 0; j < 8; ++j) {
        const int d = d0 + j;
        const float mean = sums[d] * (1.f / NPTS);
        const float var = sums[CC + d] * (1.f / NPTS) - mean * mean;
        const float sc = gamma[d] * rsqrtf(var + EPSV);
        const float x = (j < 4 ? v0[j] : v1[j - 4]);
        o[j] = f2bf(fmaxf((x - mean) * sc + beta[d], 0.f));
    }
    *(us8_t*)(buf + base) = o;
}

// ---------------------------------------------------------------------------
// BN + residual + ReLU, in place on d_out.
// ---------------------------------------------------------------------------
__global__ __launch_bounds__(256) void bn_res_relu_kernel(
    float* __restrict__ out, const float* __restrict__ sums,
    const float* __restrict__ gamma, const float* __restrict__ beta,
    const float* __restrict__ x)
{
    const size_t i = (size_t)blockIdx.x * 256 + threadIdx.x;
    const size_t base = i * 4;
    if (base >= (size_t)NPTS * CC) return;
    const int d0 = (int)(base & (CC - 1));
    float4 v = ((const float4*)out)[i];
    float4 rx = ((const float4*)x)[i];
    float r[4] = {v.x, v.y, v.z, v.w};
    const float rxf[4] = {rx.x, rx.y, rx.z, rx.w};
#pragma unroll
    for (int j = 0; j < 4; ++j) {
        const int d = d0 + j;
        const float mean = sums[d] * (1.f / NPTS);
        const float var = sums[CC + d] * (1.f / NPTS) - mean * mean;
        const float sc = gamma[d] * rsqrtf(var + EPSV);
        r[j] = fmaxf((r[j] - mean) * sc + beta[d] + rxf[j], 0.f);
    }
    ((float4*)out)[i] = make_float4(r[0], r[1], r[2], r[3]);
}

extern "C" void kernel_launch(void* const* d_in, const int* in_sizes, int n_in,
                              void* d_out, int out_size, void* d_ws, size_t ws_size,
                              hipStream_t stream) {
    const float* x   = (const float*)d_in[0];
    const float* W1  = (const float*)d_in[1];
    const float* b1  = (const float*)d_in[2];
    const float* g1  = (const float*)d_in[3];
    const float* be1 = (const float*)d_in[4];
    const float* W2  = (const float*)d_in[5];
    const float* b2  = (const float*)d_in[6];
    const float* g2  = (const float*)d_in[7];
    const float* be2 = (const float*)d_in[8];
    const int* nbr1  = (const int*)d_in[9];
    const int* mask1 = (const int*)d_in[10];
    const int* nbr2  = (const int*)d_in[11];
    const int* mask2 = (const int*)d_in[12];

    float* out = (float*)d_out;

    // workspace (~26 MB): sums | xbuf (bf16, reused) | Wt1 | Wt2
    float* sums          = (float*)d_ws;                      // 256 floats
    unsigned short* xbuf = (unsigned short*)((char*)d_ws + 1024);
    unsigned short* Wt1  = xbuf + (size_t)NPTS * CC;
    unsigned short* Wt2  = Wt1 + KK * CC * CC;

    hipMemsetAsync(d_ws, 0, 1024, stream);

    const int cvt_blocks = WBLOCKS + (NPTS * CC / 8 + 255) / 256; // 216 + 6250

    cvt_all<<<cvt_blocks, 256, 0, stream>>>(x, W1, W2, xbuf, Wt1, Wt2);
    // conv1: h1 -> d_out (fp32) + stats in sums[0:64]
    conv_mfma<<<NPTS / 128, 256, 0, stream>>>(xbuf, Wt1, b1, nbr1, mask1, out, sums);
    // BN+ReLU -> bf16 xbuf (reuse)
    bn_relu_bf16<<<(NPTS * CC / 8 + 255) / 256, 256, 0, stream>>>(out, sums, g1, be1, xbuf);
    // conv2: -> d_out (fp32) + stats in sums[64:128]
    conv_mfma<<<NPTS / 128, 256, 0, stream>>>(xbuf, Wt2, b2, nbr2, mask2, out, sums + 64);
    // BN + residual + ReLU in place
    bn_res_relu_kernel<<<(NPTS * CC / 4 + 255) / 256, 256, 0, stream>>>(out, sums + 64, g2, be2, x);
}